// Round 1
// baseline (1771.407 us; speedup 1.0000x reference)
//
#include <hip/hip_runtime.h>
#include <math.h>

#define H 128

// ---------------- CSR build ----------------

__global__ void hist_kernel(const int* __restrict__ dst, int* __restrict__ cnt, int E) {
    int e = blockIdx.x * blockDim.x + threadIdx.x;
    if (e < E) atomicAdd(&cnt[dst[e]], 1);
}

__global__ void scanA_kernel(const int* __restrict__ cnt, int* __restrict__ rowptr,
                             int* __restrict__ bsum, int N) {
    __shared__ int s[256];
    int i = blockIdx.x * 256 + threadIdx.x;
    int v = (i < N) ? cnt[i] : 0;
    s[threadIdx.x] = v;
    __syncthreads();
    for (int off = 1; off < 256; off <<= 1) {
        int t = 0;
        if (threadIdx.x >= off) t = s[threadIdx.x - off];
        __syncthreads();
        s[threadIdx.x] += t;
        __syncthreads();
    }
    if (i < N) rowptr[i] = s[threadIdx.x] - v;      // exclusive within block
    if (threadIdx.x == 255) bsum[blockIdx.x] = s[255];
}

__global__ void scanB_kernel(const int* __restrict__ bsum, int* __restrict__ bsum2, int nb) {
    __shared__ int s[1024];
    int t = threadIdx.x;
    int v0 = (t < nb) ? bsum[t] : 0;
    s[t] = v0;
    __syncthreads();
    for (int off = 1; off < 1024; off <<= 1) {
        int v = 0;
        if (t >= off) v = s[t - off];
        __syncthreads();
        s[t] += v;
        __syncthreads();
    }
    bsum2[t] = s[t] - v0;                            // exclusive
}

__global__ void scanC_kernel(int* __restrict__ rowptr, const int* __restrict__ bsum2,
                             int* __restrict__ cursor, const int* __restrict__ cnt,
                             float* __restrict__ dinv, int N, int E) {
    int i = blockIdx.x * 256 + threadIdx.x;
    if (i < N) {
        int r = rowptr[i] + bsum2[blockIdx.x];
        rowptr[i] = r;
        cursor[i] = r;
        dinv[i] = rsqrtf((float)(cnt[i] + 1));       // +1 = self loop
    }
    if (i == 0 && blockIdx.x == 0) rowptr[N] = E;
}

__global__ void scatter_kernel(const int* __restrict__ src, const int* __restrict__ dst,
                               int* __restrict__ cursor, int* __restrict__ col, int E) {
    int e = blockIdx.x * blockDim.x + threadIdx.x;
    if (e < E) {
        int d = dst[e];
        int p = atomicAdd(&cursor[d], 1);
        col[p] = src[e];
    }
}

// ---------------- GEMM: C[n,128] = (A[n,128] @ W[128,128]) * scale[n] ----------------
// 64 rows/block, 256 threads: 4 wave-groups each own a 32-col slice.
// A tile staged in LDS (pad 129 -> conflict-free b32 reads); W read wave-uniform
// (readfirstlane on the col base) so the compiler emits s_load + v_fmac.

__global__ __launch_bounds__(256) void gemm128_kernel(const float* __restrict__ A,
        const float* __restrict__ W, const float* __restrict__ scale,
        float* __restrict__ C, int N) {
    __shared__ float As[64][H + 1];
    int tid = threadIdx.x;
    int r0 = blockIdx.x * 64;

    #pragma unroll
    for (int i = 0; i < 8; ++i) {
        int lin = tid + i * 256;          // float4 index, 2048 total
        int r = lin >> 5;                 // 32 float4 per row
        int c4 = (lin & 31) << 2;
        float4 v = make_float4(0.f, 0.f, 0.f, 0.f);
        if (r0 + r < N) v = *(const float4*)&A[(size_t)(r0 + r) * H + c4];
        As[r][c4 + 0] = v.x; As[r][c4 + 1] = v.y;
        As[r][c4 + 2] = v.z; As[r][c4 + 3] = v.w;
    }
    __syncthreads();

    int row = tid & 63;
    int c0 = __builtin_amdgcn_readfirstlane((tid >> 6) << 5);

    float acc[32];
    #pragma unroll
    for (int j = 0; j < 32; ++j) acc[j] = 0.f;

    for (int k = 0; k < H; ++k) {
        float a = As[row][k];
        #pragma unroll
        for (int j = 0; j < 32; ++j)
            acc[j] = fmaf(a, W[k * H + c0 + j], acc[j]);
    }

    int gr = r0 + row;
    if (gr < N) {
        float s = scale ? scale[gr] : 1.0f;
        #pragma unroll
        for (int j = 0; j < 32; j += 4) {
            float4 v = make_float4(acc[j] * s, acc[j + 1] * s, acc[j + 2] * s, acc[j + 3] * s);
            *(float4*)&C[(size_t)gr * H + c0 + j] = v;
        }
    }
}

// ---------------- SpMM pull: out[d] = tanh(dinv[d]*(lin'[d] + sum_e lin'[col[e]]) + b) ----
// lin' is pre-scaled by dinv[src] in the GEMM epilogue, so the self-loop term is
// just lin'[d]. One block of 128 threads per node; col[e]/rowptr are
// block-uniform -> scalar loads; the gather is one coalesced 512B row read.

__global__ __launch_bounds__(128) void spmm_kernel(const float* __restrict__ lin,
        const int* __restrict__ rowptr, const int* __restrict__ col,
        const float* __restrict__ dinv, const float* __restrict__ bias,
        float* __restrict__ out, int N) {
    int node = blockIdx.x;
    int f = threadIdx.x;
    int beg = rowptr[node];
    int end = rowptr[node + 1];
    float acc = lin[(size_t)node * H + f];            // self loop (pre-scaled)
    for (int e = beg; e < end; ++e) {
        int s = col[e];
        acc += lin[(size_t)s * H + f];
    }
    acc = fmaf(acc, dinv[node], bias[f]);
    out[(size_t)node * H + f] = tanhf(acc);
}

// ---------------- Classifier: out[n,c] = h[n,:] . Wc[:,c] + bc[c] ----------------

__global__ void classifier_kernel(const float* __restrict__ h, const float* __restrict__ Wc,
        const float* __restrict__ bc, float* __restrict__ out, int N, int Cout) {
    int idx = blockIdx.x * blockDim.x + threadIdx.x;
    if (idx >= N * Cout) return;
    int n = idx / Cout, c = idx - (idx / Cout) * Cout;
    float acc = bc[c];
    const float* hr = h + (size_t)n * H;
    #pragma unroll
    for (int k = 0; k < H; ++k) acc = fmaf(hr[k], Wc[k * Cout + c], acc);
    out[idx] = acc;
}

// ---------------- launch ----------------

extern "C" void kernel_launch(void* const* d_in, const int* in_sizes, int n_in,
                              void* d_out, int out_size, void* d_ws, size_t ws_size,
                              hipStream_t stream) {
    const float* x  = (const float*)d_in[0];
    const int* eidx = (const int*)d_in[1];
    const float* W1 = (const float*)d_in[2];
    const float* b1 = (const float*)d_in[3];
    const float* W2 = (const float*)d_in[4];
    const float* b2 = (const float*)d_in[5];
    const float* W3 = (const float*)d_in[6];
    const float* b3 = (const float*)d_in[7];
    const float* Wc = (const float*)d_in[8];
    const float* bc = (const float*)d_in[9];

    int N    = in_sizes[0] / H;       // 100000
    int E    = in_sizes[1] / 2;       // 3200000
    int Cout = in_sizes[8] / H;       // 40

    const int* srcp = eidx;
    const int* dstp = eidx + E;

    float* out  = (float*)d_out;
    float* hOut = out + (size_t)N * Cout;   // h output region doubles as ping buffer

    char* p = (char*)d_ws;
    float* hA     = (float*)p;  p += (size_t)N * H * 4;
    int*   col    = (int*)p;    p += (size_t)E * 4;
    int*   cnt    = (int*)p;    p += (size_t)N * 4;
    int*   rowptr = (int*)p;    p += (size_t)(N + 1) * 4;
    int*   cursor = (int*)p;    p += (size_t)N * 4;
    float* dinv   = (float*)p;  p += (size_t)N * 4;
    int*   bsum   = (int*)p;    p += 1024 * 4;
    int*   bsum2  = (int*)p;    p += 1024 * 4;

    int nb = (N + 255) / 256;
    int ge = (E + 255) / 256;
    int gg = (N + 63) / 64;

    hipMemsetAsync(cnt, 0, (size_t)N * 4, stream);
    hist_kernel<<<ge, 256, 0, stream>>>(dstp, cnt, E);
    scanA_kernel<<<nb, 256, 0, stream>>>(cnt, rowptr, bsum, N);
    scanB_kernel<<<1, 1024, 0, stream>>>(bsum, bsum2, nb);
    scanC_kernel<<<nb, 256, 0, stream>>>(rowptr, bsum2, cursor, cnt, dinv, N, E);
    scatter_kernel<<<ge, 256, 0, stream>>>(srcp, dstp, cursor, col, E);

    // layer 1
    gemm128_kernel<<<gg, 256, 0, stream>>>(x, W1, dinv, hA, N);
    spmm_kernel<<<N, 128, 0, stream>>>(hA, rowptr, col, dinv, b1, hOut, N);
    // layer 2
    gemm128_kernel<<<gg, 256, 0, stream>>>(hOut, W2, dinv, hA, N);
    spmm_kernel<<<N, 128, 0, stream>>>(hA, rowptr, col, dinv, b2, hOut, N);
    // layer 3
    gemm128_kernel<<<gg, 256, 0, stream>>>(hOut, W3, dinv, hA, N);
    spmm_kernel<<<N, 128, 0, stream>>>(hA, rowptr, col, dinv, b3, hOut, N);
    // classifier
    classifier_kernel<<<(N * Cout + 255) / 256, 256, 0, stream>>>(hOut, Wc, bc, out, N, Cout);
}

// Round 2
// 1535.322 us; speedup vs baseline: 1.1538x; 1.1538x over previous
//
#include <hip/hip_runtime.h>
#include <math.h>

#define H 128

// ---------------- CSR build ----------------

__global__ void hist_kernel(const int* __restrict__ dst, int* __restrict__ cnt, int E) {
    int e = blockIdx.x * blockDim.x + threadIdx.x;
    if (e < E) atomicAdd(&cnt[dst[e]], 1);
}

__global__ void scanA_kernel(const int* __restrict__ cnt, int* __restrict__ rowptr,
                             int* __restrict__ bsum, int N) {
    __shared__ int s[256];
    int i = blockIdx.x * 256 + threadIdx.x;
    int v = (i < N) ? cnt[i] : 0;
    s[threadIdx.x] = v;
    __syncthreads();
    for (int off = 1; off < 256; off <<= 1) {
        int t = 0;
        if (threadIdx.x >= off) t = s[threadIdx.x - off];
        __syncthreads();
        s[threadIdx.x] += t;
        __syncthreads();
    }
    if (i < N) rowptr[i] = s[threadIdx.x] - v;      // exclusive within block
    if (threadIdx.x == 255) bsum[blockIdx.x] = s[255];
}

__global__ void scanB_kernel(const int* __restrict__ bsum, int* __restrict__ bsum2, int nb) {
    __shared__ int s[1024];
    int t = threadIdx.x;
    int v0 = (t < nb) ? bsum[t] : 0;
    s[t] = v0;
    __syncthreads();
    for (int off = 1; off < 1024; off <<= 1) {
        int v = 0;
        if (t >= off) v = s[t - off];
        __syncthreads();
        s[t] += v;
        __syncthreads();
    }
    bsum2[t] = s[t] - v0;                            // exclusive
}

__global__ void scanC_kernel(int* __restrict__ rowptr, const int* __restrict__ bsum2,
                             int* __restrict__ cursor, const int* __restrict__ cnt,
                             float* __restrict__ dinv, int N, int E) {
    int i = blockIdx.x * 256 + threadIdx.x;
    if (i < N) {
        int r = rowptr[i] + bsum2[blockIdx.x];
        rowptr[i] = r;
        cursor[i] = r;
        dinv[i] = rsqrtf((float)(cnt[i] + 1));       // +1 = self loop
    }
    if (i == 0 && blockIdx.x == 0) rowptr[N] = E;
}

__global__ void scatter_kernel(const int* __restrict__ src, const int* __restrict__ dst,
                               int* __restrict__ cursor, int* __restrict__ col, int E) {
    int e = blockIdx.x * blockDim.x + threadIdx.x;
    if (e < E) {
        int d = dst[e];
        int p = atomicAdd(&cursor[d], 1);
        col[p] = src[e];
    }
}

// ---------------- GEMM: C[n,128] = (A[n,128] @ W[128,128]) * scale[n] ----------------

__global__ __launch_bounds__(256) void gemm128_kernel(const float* __restrict__ A,
        const float* __restrict__ W, const float* __restrict__ scale,
        float* __restrict__ C, int N) {
    __shared__ float As[64][H + 1];
    int tid = threadIdx.x;
    int r0 = blockIdx.x * 64;

    #pragma unroll
    for (int i = 0; i < 8; ++i) {
        int lin = tid + i * 256;          // float4 index, 2048 total
        int r = lin >> 5;                 // 32 float4 per row
        int c4 = (lin & 31) << 2;
        float4 v = make_float4(0.f, 0.f, 0.f, 0.f);
        if (r0 + r < N) v = *(const float4*)&A[(size_t)(r0 + r) * H + c4];
        As[r][c4 + 0] = v.x; As[r][c4 + 1] = v.y;
        As[r][c4 + 2] = v.z; As[r][c4 + 3] = v.w;
    }
    __syncthreads();

    int row = tid & 63;
    int c0 = __builtin_amdgcn_readfirstlane((tid >> 6) << 5);

    float acc[32];
    #pragma unroll
    for (int j = 0; j < 32; ++j) acc[j] = 0.f;

    for (int k = 0; k < H; ++k) {
        float a = As[row][k];
        #pragma unroll
        for (int j = 0; j < 32; ++j)
            acc[j] = fmaf(a, W[k * H + c0 + j], acc[j]);
    }

    int gr = r0 + row;
    if (gr < N) {
        float s = scale ? scale[gr] : 1.0f;
        #pragma unroll
        for (int j = 0; j < 32; j += 4) {
            float4 v = make_float4(acc[j] * s, acc[j + 1] * s, acc[j + 2] * s, acc[j + 3] * s);
            *(float4*)&C[(size_t)gr * H + c0 + j] = v;
        }
    }
}

// ---------------- SpMM pull, MLP-optimized ----------------
// thread = (node, float4 chunk): 32 threads per node, 8 nodes per 256-block.
// Edge loop unrolled x4 with independent accumulators -> 4 gathers + 4 col
// loads in flight per thread; 3.2M threads of TLP on top.

__global__ __launch_bounds__(256) void spmm_kernel(const float* __restrict__ lin,
        const int* __restrict__ rowptr, const int* __restrict__ col,
        const float* __restrict__ dinv, const float* __restrict__ bias,
        float* __restrict__ out, int N) {
    int tid = threadIdx.x;
    int node = blockIdx.x * 8 + (tid >> 5);
    if (node >= N) return;
    int c4 = (tid & 31) << 2;

    int beg = rowptr[node];
    int end = rowptr[node + 1];

    const float4* linv = (const float4*)lin;
    int cq = c4 >> 2;                                  // float4 index within row

    float4 a0 = linv[(size_t)node * 32 + cq];          // self loop (pre-scaled)
    float4 a1 = make_float4(0.f, 0.f, 0.f, 0.f);
    float4 a2 = make_float4(0.f, 0.f, 0.f, 0.f);
    float4 a3 = make_float4(0.f, 0.f, 0.f, 0.f);

    int e = beg;
    for (; e + 4 <= end; e += 4) {
        int s0 = col[e], s1 = col[e + 1], s2 = col[e + 2], s3 = col[e + 3];
        float4 v0 = linv[(size_t)s0 * 32 + cq];
        float4 v1 = linv[(size_t)s1 * 32 + cq];
        float4 v2 = linv[(size_t)s2 * 32 + cq];
        float4 v3 = linv[(size_t)s3 * 32 + cq];
        a0.x += v0.x; a0.y += v0.y; a0.z += v0.z; a0.w += v0.w;
        a1.x += v1.x; a1.y += v1.y; a1.z += v1.z; a1.w += v1.w;
        a2.x += v2.x; a2.y += v2.y; a2.z += v2.z; a2.w += v2.w;
        a3.x += v3.x; a3.y += v3.y; a3.z += v3.z; a3.w += v3.w;
    }
    for (; e < end; ++e) {
        int s = col[e];
        float4 v = linv[(size_t)s * 32 + cq];
        a0.x += v.x; a0.y += v.y; a0.z += v.z; a0.w += v.w;
    }

    float d = dinv[node];
    float4 r;
    r.x = tanhf(fmaf(a0.x + a1.x + a2.x + a3.x, d, bias[c4 + 0]));
    r.y = tanhf(fmaf(a0.y + a1.y + a2.y + a3.y, d, bias[c4 + 1]));
    r.z = tanhf(fmaf(a0.z + a1.z + a2.z + a3.z, d, bias[c4 + 2]));
    r.w = tanhf(fmaf(a0.w + a1.w + a2.w + a3.w, d, bias[c4 + 3]));
    ((float4*)out)[(size_t)node * 32 + cq] = r;
}

// ---------------- Classifier ----------------

__global__ void classifier_kernel(const float* __restrict__ h, const float* __restrict__ Wc,
        const float* __restrict__ bc, float* __restrict__ out, int N, int Cout) {
    int idx = blockIdx.x * blockDim.x + threadIdx.x;
    if (idx >= N * Cout) return;
    int n = idx / Cout, c = idx - (idx / Cout) * Cout;
    float acc = bc[c];
    const float* hr = h + (size_t)n * H;
    #pragma unroll
    for (int k = 0; k < H; ++k) acc = fmaf(hr[k], Wc[k * Cout + c], acc);
    out[idx] = acc;
}

// ---------------- launch ----------------

extern "C" void kernel_launch(void* const* d_in, const int* in_sizes, int n_in,
                              void* d_out, int out_size, void* d_ws, size_t ws_size,
                              hipStream_t stream) {
    const float* x  = (const float*)d_in[0];
    const int* eidx = (const int*)d_in[1];
    const float* W1 = (const float*)d_in[2];
    const float* b1 = (const float*)d_in[3];
    const float* W2 = (const float*)d_in[4];
    const float* b2 = (const float*)d_in[5];
    const float* W3 = (const float*)d_in[6];
    const float* b3 = (const float*)d_in[7];
    const float* Wc = (const float*)d_in[8];
    const float* bc = (const float*)d_in[9];

    int N    = in_sizes[0] / H;       // 100000
    int E    = in_sizes[1] / 2;       // 3200000
    int Cout = in_sizes[8] / H;       // 40

    const int* srcp = eidx;
    const int* dstp = eidx + E;

    float* out  = (float*)d_out;
    float* hOut = out + (size_t)N * Cout;   // h output region doubles as ping buffer

    char* p = (char*)d_ws;
    float* hA     = (float*)p;  p += (size_t)N * H * 4;
    int*   col    = (int*)p;    p += (size_t)E * 4;
    int*   cnt    = (int*)p;    p += (size_t)N * 4;
    int*   rowptr = (int*)p;    p += (size_t)(N + 1) * 4;
    int*   cursor = (int*)p;    p += (size_t)N * 4;
    float* dinv   = (float*)p;  p += (size_t)N * 4;
    int*   bsum   = (int*)p;    p += 1024 * 4;
    int*   bsum2  = (int*)p;    p += 1024 * 4;

    int nb = (N + 255) / 256;
    int ge = (E + 255) / 256;
    int gg = (N + 63) / 64;
    int gs = (N + 7) / 8;

    hipMemsetAsync(cnt, 0, (size_t)N * 4, stream);
    hist_kernel<<<ge, 256, 0, stream>>>(dstp, cnt, E);
    scanA_kernel<<<nb, 256, 0, stream>>>(cnt, rowptr, bsum, N);
    scanB_kernel<<<1, 1024, 0, stream>>>(bsum, bsum2, nb);
    scanC_kernel<<<nb, 256, 0, stream>>>(rowptr, bsum2, cursor, cnt, dinv, N, E);
    scatter_kernel<<<ge, 256, 0, stream>>>(srcp, dstp, cursor, col, E);

    // layer 1
    gemm128_kernel<<<gg, 256, 0, stream>>>(x, W1, dinv, hA, N);
    spmm_kernel<<<gs, 256, 0, stream>>>(hA, rowptr, col, dinv, b1, hOut, N);
    // layer 2
    gemm128_kernel<<<gg, 256, 0, stream>>>(hOut, W2, dinv, hA, N);
    spmm_kernel<<<gs, 256, 0, stream>>>(hA, rowptr, col, dinv, b2, hOut, N);
    // layer 3
    gemm128_kernel<<<gg, 256, 0, stream>>>(hOut, W3, dinv, hA, N);
    spmm_kernel<<<gs, 256, 0, stream>>>(hA, rowptr, col, dinv, b3, hOut, N);
    // classifier
    classifier_kernel<<<(N * Cout + 255) / 256, 256, 0, stream>>>(hOut, Wc, bc, out, N, Cout);
}

// Round 3
// 1239.764 us; speedup vs baseline: 1.4288x; 1.2384x over previous
//
#include <hip/hip_runtime.h>
#include <math.h>

#define H 128
#define BSTRIDE 5120            // packed entries per bucket (mean 4096, +16 sigma)

// ---------------- CSR build: bucketed counting sort ----------------
// bucket = dst >> 7 (128 nodes per bucket). packed entry = (local_dst<<17)|src.

__global__ __launch_bounds__(256) void bin_kernel(const int* __restrict__ src,
        const int* __restrict__ dst, int* __restrict__ bucketFill,
        int* __restrict__ packed, int E, int nbk) {
    __shared__ int hcnt[1024];
    __shared__ int base[1024];
    __shared__ int cur[1024];
    int tid = threadIdx.x;
    for (int i = tid; i < nbk; i += 256) { hcnt[i] = 0; cur[i] = 0; }
    __syncthreads();
    int e0 = blockIdx.x * 8192;
    int e1 = min(e0 + 8192, E);
    for (int e = e0 + tid; e < e1; e += 256)
        atomicAdd(&hcnt[dst[e] >> 7], 1);
    __syncthreads();
    for (int i = tid; i < nbk; i += 256) {
        int c = hcnt[i];
        base[i] = c ? atomicAdd(&bucketFill[i], c) : 0;   // claim contiguous chunk
    }
    __syncthreads();
    for (int e = e0 + tid; e < e1; e += 256) {
        int d = dst[e], s = src[e];
        int b = d >> 7;
        int r = atomicAdd(&cur[b], 1);
        packed[b * BSTRIDE + base[b] + r] = ((d & 127) << 17) | s;
    }
}

__global__ void bscan_kernel(const int* __restrict__ bucketFill, int* __restrict__ bucketBase,
                             int nbk, int E, int* __restrict__ rowptrN) {
    __shared__ int s[1024];
    int t = threadIdx.x;
    int v0 = (t < nbk) ? bucketFill[t] : 0;
    s[t] = v0;
    __syncthreads();
    for (int off = 1; off < 1024; off <<= 1) {
        int v = 0;
        if (t >= off) v = s[t - off];
        __syncthreads();
        s[t] += v;
        __syncthreads();
    }
    bucketBase[t] = s[t] - v0;                 // exclusive
    if (t == 0) rowptrN[0] = E;                // rowptr[N] = E
}

// One workgroup per bucket: local hist + scan -> rowptr/dinv, then scatter col
// into this bucket's private contiguous segment (single-CU line ownership).
__global__ __launch_bounds__(256) void fine_kernel(const int* __restrict__ packed,
        const int* __restrict__ bucketFill, const int* __restrict__ bucketBase,
        int* __restrict__ rowptr, int* __restrict__ col, float* __restrict__ dinv, int N) {
    __shared__ int lcnt[128], lofs[128], lcur[128];
    int b = blockIdx.x;
    int tid = threadIdx.x;
    int m = bucketFill[b]; if (m > BSTRIDE) m = BSTRIDE;
    int base = bucketBase[b];
    int n0 = b << 7;
    if (tid < 128) lcnt[tid] = 0;
    __syncthreads();
    const int* pk = packed + (size_t)b * BSTRIDE;
    for (int i = tid; i < m; i += 256) atomicAdd(&lcnt[pk[i] >> 17], 1);
    __syncthreads();
    if (tid == 0) {
        int acc = 0;
        #pragma unroll 4
        for (int i = 0; i < 128; ++i) { lofs[i] = acc; acc += lcnt[i]; }
    }
    __syncthreads();
    if (tid < 128) {
        lcur[tid] = lofs[tid];
        int node = n0 + tid;
        if (node < N) {
            rowptr[node] = base + lofs[tid];
            dinv[node] = rsqrtf((float)(lcnt[tid] + 1));   // +1 self loop
        }
    }
    __syncthreads();
    for (int i = tid; i < m; i += 256) {
        int p = pk[i];
        int ld = p >> 17, s = p & 131071;
        int r = atomicAdd(&lcur[ld], 1);
        col[base + r] = s;
    }
}

// ---------------- GEMM: C[n,128] = (A[n,128] @ W[128,128]) * scale[n] ----------------

__global__ __launch_bounds__(256) void gemm128_kernel(const float* __restrict__ A,
        const float* __restrict__ W, const float* __restrict__ scale,
        float* __restrict__ C, int N) {
    __shared__ float As[64][H + 1];
    int tid = threadIdx.x;
    int r0 = blockIdx.x * 64;

    #pragma unroll
    for (int i = 0; i < 8; ++i) {
        int lin = tid + i * 256;          // float4 index, 2048 total
        int r = lin >> 5;                 // 32 float4 per row
        int c4 = (lin & 31) << 2;
        float4 v = make_float4(0.f, 0.f, 0.f, 0.f);
        if (r0 + r < N) v = *(const float4*)&A[(size_t)(r0 + r) * H + c4];
        As[r][c4 + 0] = v.x; As[r][c4 + 1] = v.y;
        As[r][c4 + 2] = v.z; As[r][c4 + 3] = v.w;
    }
    __syncthreads();

    int row = tid & 63;
    int c0 = __builtin_amdgcn_readfirstlane((tid >> 6) << 5);

    float acc[32];
    #pragma unroll
    for (int j = 0; j < 32; ++j) acc[j] = 0.f;

    for (int k = 0; k < H; ++k) {
        float a = As[row][k];
        #pragma unroll
        for (int j = 0; j < 32; ++j)
            acc[j] = fmaf(a, W[k * H + c0 + j], acc[j]);
    }

    int gr = r0 + row;
    if (gr < N) {
        float s = scale ? scale[gr] : 1.0f;
        #pragma unroll
        for (int j = 0; j < 32; j += 4) {
            float4 v = make_float4(acc[j] * s, acc[j + 1] * s, acc[j + 2] * s, acc[j + 3] * s);
            *(float4*)&C[(size_t)gr * H + c0 + j] = v;
        }
    }
}

// ---------------- SpMM pull ----------------

__global__ __launch_bounds__(256) void spmm_kernel(const float* __restrict__ lin,
        const int* __restrict__ rowptr, const int* __restrict__ col,
        const float* __restrict__ dinv, const float* __restrict__ bias,
        float* __restrict__ out, int N) {
    int tid = threadIdx.x;
    int node = blockIdx.x * 8 + (tid >> 5);
    if (node >= N) return;
    int c4 = (tid & 31) << 2;

    int beg = rowptr[node];
    int end = rowptr[node + 1];

    const float4* linv = (const float4*)lin;
    int cq = c4 >> 2;

    float4 a0 = linv[(size_t)node * 32 + cq];          // self loop (pre-scaled)
    float4 a1 = make_float4(0.f, 0.f, 0.f, 0.f);
    float4 a2 = make_float4(0.f, 0.f, 0.f, 0.f);
    float4 a3 = make_float4(0.f, 0.f, 0.f, 0.f);

    int e = beg;
    for (; e + 4 <= end; e += 4) {
        int s0 = col[e], s1 = col[e + 1], s2 = col[e + 2], s3 = col[e + 3];
        float4 v0 = linv[(size_t)s0 * 32 + cq];
        float4 v1 = linv[(size_t)s1 * 32 + cq];
        float4 v2 = linv[(size_t)s2 * 32 + cq];
        float4 v3 = linv[(size_t)s3 * 32 + cq];
        a0.x += v0.x; a0.y += v0.y; a0.z += v0.z; a0.w += v0.w;
        a1.x += v1.x; a1.y += v1.y; a1.z += v1.z; a1.w += v1.w;
        a2.x += v2.x; a2.y += v2.y; a2.z += v2.z; a2.w += v2.w;
        a3.x += v3.x; a3.y += v3.y; a3.z += v3.z; a3.w += v3.w;
    }
    for (; e < end; ++e) {
        int s = col[e];
        float4 v = linv[(size_t)s * 32 + cq];
        a0.x += v.x; a0.y += v.y; a0.z += v.z; a0.w += v.w;
    }

    float d = dinv[node];
    float4 r;
    r.x = tanhf(fmaf(a0.x + a1.x + a2.x + a3.x, d, bias[c4 + 0]));
    r.y = tanhf(fmaf(a0.y + a1.y + a2.y + a3.y, d, bias[c4 + 1]));
    r.z = tanhf(fmaf(a0.z + a1.z + a2.z + a3.z, d, bias[c4 + 2]));
    r.w = tanhf(fmaf(a0.w + a1.w + a2.w + a3.w, d, bias[c4 + 3]));
    ((float4*)out)[(size_t)node * 32 + cq] = r;
}

// ---------------- Classifier ----------------

__global__ void classifier_kernel(const float* __restrict__ h, const float* __restrict__ Wc,
        const float* __restrict__ bc, float* __restrict__ out, int N, int Cout) {
    int idx = blockIdx.x * blockDim.x + threadIdx.x;
    if (idx >= N * Cout) return;
    int n = idx / Cout, c = idx - (idx / Cout) * Cout;
    float acc = bc[c];
    const float* hr = h + (size_t)n * H;
    #pragma unroll
    for (int k = 0; k < H; ++k) acc = fmaf(hr[k], Wc[k * Cout + c], acc);
    out[idx] = acc;
}

// ---------------- launch ----------------

extern "C" void kernel_launch(void* const* d_in, const int* in_sizes, int n_in,
                              void* d_out, int out_size, void* d_ws, size_t ws_size,
                              hipStream_t stream) {
    const float* x  = (const float*)d_in[0];
    const int* eidx = (const int*)d_in[1];
    const float* W1 = (const float*)d_in[2];
    const float* b1 = (const float*)d_in[3];
    const float* W2 = (const float*)d_in[4];
    const float* b2 = (const float*)d_in[5];
    const float* W3 = (const float*)d_in[6];
    const float* b3 = (const float*)d_in[7];
    const float* Wc = (const float*)d_in[8];
    const float* bc = (const float*)d_in[9];

    int N    = in_sizes[0] / H;       // 100000
    int E    = in_sizes[1] / 2;       // 3200000
    int Cout = in_sizes[8] / H;       // 40
    int nbk  = (N + 127) >> 7;        // 782 buckets

    const int* srcp = eidx;
    const int* dstp = eidx + E;

    float* out  = (float*)d_out;
    float* hOut = out + (size_t)N * Cout;   // h output region doubles as ping buffer

    char* p = (char*)d_ws;
    float* hA       = (float*)p;  p += (size_t)N * H * 4;
    int*   col      = (int*)p;    p += (size_t)E * 4;
    int*   rowptr   = (int*)p;    p += (size_t)(N + 1) * 4;
    float* dinv     = (float*)p;  p += (size_t)N * 4;
    int*   bFill    = (int*)p;    p += 1024 * 4;
    int*   bBase    = (int*)p;    p += 1024 * 4;
    int*   packed   = (int*)hA;   // aliases hA: consumed by fine_kernel before gemm1 writes hA

    int gg = (N + 63) / 64;
    int gs = (N + 7) / 8;
    int gb = (E + 8191) / 8192;

    hipMemsetAsync(bFill, 0, (size_t)nbk * 4, stream);
    bin_kernel<<<gb, 256, 0, stream>>>(srcp, dstp, bFill, packed, E, nbk);
    bscan_kernel<<<1, 1024, 0, stream>>>(bFill, bBase, nbk, E, rowptr + N);
    fine_kernel<<<nbk, 256, 0, stream>>>(packed, bFill, bBase, rowptr, col, dinv, N);

    // layer 1
    gemm128_kernel<<<gg, 256, 0, stream>>>(x, W1, dinv, hA, N);
    spmm_kernel<<<gs, 256, 0, stream>>>(hA, rowptr, col, dinv, b1, hOut, N);
    // layer 2
    gemm128_kernel<<<gg, 256, 0, stream>>>(hOut, W2, dinv, hA, N);
    spmm_kernel<<<gs, 256, 0, stream>>>(hA, rowptr, col, dinv, b2, hOut, N);
    // layer 3
    gemm128_kernel<<<gg, 256, 0, stream>>>(hOut, W3, dinv, hA, N);
    spmm_kernel<<<gs, 256, 0, stream>>>(hA, rowptr, col, dinv, b3, hOut, N);
    // classifier
    classifier_kernel<<<(N * Cout + 255) / 256, 256, 0, stream>>>(hOut, Wc, bc, out, N, Cout);
}

// Round 4
// 889.057 us; speedup vs baseline: 1.9925x; 1.3945x over previous
//
#include <hip/hip_runtime.h>
#include <hip/hip_fp16.h>
#include <math.h>

#define H 128
#define BSTRIDE 5120            // packed entries per bucket (mean 4096, +16 sigma)

// ---------------- CSR build: bucketed counting sort ----------------
// bucket = dst >> 7 (128 nodes per bucket). packed entry = (local_dst<<17)|src.

__global__ __launch_bounds__(256) void bin_kernel(const int* __restrict__ src,
        const int* __restrict__ dst, int* __restrict__ bucketFill,
        int* __restrict__ packed, int E, int nbk) {
    __shared__ int hcnt[1024];
    __shared__ int base[1024];
    __shared__ int cur[1024];
    int tid = threadIdx.x;
    for (int i = tid; i < nbk; i += 256) { hcnt[i] = 0; cur[i] = 0; }
    __syncthreads();
    int e0 = blockIdx.x * 8192;
    int e1 = min(e0 + 8192, E);
    for (int e = e0 + tid; e < e1; e += 256)
        atomicAdd(&hcnt[dst[e] >> 7], 1);
    __syncthreads();
    for (int i = tid; i < nbk; i += 256) {
        int c = hcnt[i];
        base[i] = c ? atomicAdd(&bucketFill[i], c) : 0;   // claim contiguous chunk
    }
    __syncthreads();
    for (int e = e0 + tid; e < e1; e += 256) {
        int d = dst[e], s = src[e];
        int b = d >> 7;
        int r = atomicAdd(&cur[b], 1);
        packed[b * BSTRIDE + base[b] + r] = ((d & 127) << 17) | s;
    }
}

__global__ void bscan_kernel(const int* __restrict__ bucketFill, int* __restrict__ bucketBase,
                             int nbk, int E, int* __restrict__ rowptrN) {
    __shared__ int s[1024];
    int t = threadIdx.x;
    int v0 = (t < nbk) ? bucketFill[t] : 0;
    s[t] = v0;
    __syncthreads();
    for (int off = 1; off < 1024; off <<= 1) {
        int v = 0;
        if (t >= off) v = s[t - off];
        __syncthreads();
        s[t] += v;
        __syncthreads();
    }
    bucketBase[t] = s[t] - v0;                 // exclusive
    if (t == 0) rowptrN[0] = E;                // rowptr[N] = E
}

__global__ __launch_bounds__(256) void fine_kernel(const int* __restrict__ packed,
        const int* __restrict__ bucketFill, const int* __restrict__ bucketBase,
        int* __restrict__ rowptr, int* __restrict__ col, float* __restrict__ dinv, int N) {
    __shared__ int lcnt[128], lofs[128], lcur[128];
    int b = blockIdx.x;
    int tid = threadIdx.x;
    int m = bucketFill[b]; if (m > BSTRIDE) m = BSTRIDE;
    int base = bucketBase[b];
    int n0 = b << 7;
    if (tid < 128) lcnt[tid] = 0;
    __syncthreads();
    const int* pk = packed + (size_t)b * BSTRIDE;
    for (int i = tid; i < m; i += 256) atomicAdd(&lcnt[pk[i] >> 17], 1);
    __syncthreads();
    if (tid == 0) {
        int acc = 0;
        #pragma unroll 4
        for (int i = 0; i < 128; ++i) { lofs[i] = acc; acc += lcnt[i]; }
    }
    __syncthreads();
    if (tid < 128) {
        lcur[tid] = lofs[tid];
        int node = n0 + tid;
        if (node < N) {
            rowptr[node] = base + lofs[tid];
            dinv[node] = rsqrtf((float)(lcnt[tid] + 1));   // +1 self loop
        }
    }
    __syncthreads();
    for (int i = tid; i < m; i += 256) {
        int p = pk[i];
        int ld = p >> 17, s = p & 131071;
        int r = atomicAdd(&lcur[ld], 1);
        col[base + r] = s;
    }
}

// ---------------- GEMM: C[n,128] = fp16((A[n,128] @ W[128,128]) * scale[n]) ----------------

__device__ inline unsigned pack2(float x, float y) {
    __half2 h = __floats2half2_rn(x, y);
    return *(unsigned*)&h;
}

__global__ __launch_bounds__(256) void gemm128_kernel(const float* __restrict__ A,
        const float* __restrict__ W, const float* __restrict__ scale,
        unsigned short* __restrict__ C, int N) {
    __shared__ float As[64][H + 1];
    int tid = threadIdx.x;
    int r0 = blockIdx.x * 64;

    #pragma unroll
    for (int i = 0; i < 8; ++i) {
        int lin = tid + i * 256;          // float4 index, 2048 total
        int r = lin >> 5;                 // 32 float4 per row
        int c4 = (lin & 31) << 2;
        float4 v = make_float4(0.f, 0.f, 0.f, 0.f);
        if (r0 + r < N) v = *(const float4*)&A[(size_t)(r0 + r) * H + c4];
        As[r][c4 + 0] = v.x; As[r][c4 + 1] = v.y;
        As[r][c4 + 2] = v.z; As[r][c4 + 3] = v.w;
    }
    __syncthreads();

    int row = tid & 63;
    int c0 = __builtin_amdgcn_readfirstlane((tid >> 6) << 5);

    float acc[32];
    #pragma unroll
    for (int j = 0; j < 32; ++j) acc[j] = 0.f;

    for (int k = 0; k < H; ++k) {
        float a = As[row][k];
        #pragma unroll
        for (int j = 0; j < 32; ++j)
            acc[j] = fmaf(a, W[k * H + c0 + j], acc[j]);
    }

    int gr = r0 + row;
    if (gr < N) {
        float s = scale[gr];
        unsigned short* Crow = C + (size_t)gr * H;
        #pragma unroll
        for (int j = 0; j < 32; j += 8) {
            uint4 w;
            w.x = pack2(acc[j + 0] * s, acc[j + 1] * s);
            w.y = pack2(acc[j + 2] * s, acc[j + 3] * s);
            w.z = pack2(acc[j + 4] * s, acc[j + 5] * s);
            w.w = pack2(acc[j + 6] * s, acc[j + 7] * s);
            *(uint4*)&Crow[c0 + j] = w;
        }
    }
}

// ---------------- SpMM pull (fp16 gather table, fp32 accumulate/output) ----------------
// 16 threads/node, each owns 8 features (one 16B uint4 of the 256B fp16 row).

__device__ inline void add8(float* a, uint4 v) {
    float2 f;
    f = __half22float2(*(const __half2*)&v.x); a[0] += f.x; a[1] += f.y;
    f = __half22float2(*(const __half2*)&v.y); a[2] += f.x; a[3] += f.y;
    f = __half22float2(*(const __half2*)&v.z); a[4] += f.x; a[5] += f.y;
    f = __half22float2(*(const __half2*)&v.w); a[6] += f.x; a[7] += f.y;
}

__global__ __launch_bounds__(256) void spmm_kernel(const unsigned short* __restrict__ lin,
        const int* __restrict__ rowptr, const int* __restrict__ col,
        const float* __restrict__ dinv, const float* __restrict__ bias,
        float* __restrict__ out, int N) {
    int tid = threadIdx.x;
    int node = blockIdx.x * 16 + (tid >> 4);
    if (node >= N) return;
    int cq = tid & 15;                                 // 16B chunk within row

    int beg = rowptr[node];
    int end = rowptr[node + 1];

    const uint4* linv = (const uint4*)lin;

    float acc[8];
    {
        uint4 sv = linv[(size_t)node * 16 + cq];       // self loop (pre-scaled)
        float2 f;
        f = __half22float2(*(const __half2*)&sv.x); acc[0] = f.x; acc[1] = f.y;
        f = __half22float2(*(const __half2*)&sv.y); acc[2] = f.x; acc[3] = f.y;
        f = __half22float2(*(const __half2*)&sv.z); acc[4] = f.x; acc[5] = f.y;
        f = __half22float2(*(const __half2*)&sv.w); acc[6] = f.x; acc[7] = f.y;
    }

    int e = beg;
    for (; e + 4 <= end; e += 4) {
        int s0 = col[e], s1 = col[e + 1], s2 = col[e + 2], s3 = col[e + 3];
        uint4 v0 = linv[(size_t)s0 * 16 + cq];
        uint4 v1 = linv[(size_t)s1 * 16 + cq];
        uint4 v2 = linv[(size_t)s2 * 16 + cq];
        uint4 v3 = linv[(size_t)s3 * 16 + cq];
        add8(acc, v0);
        add8(acc, v1);
        add8(acc, v2);
        add8(acc, v3);
    }
    for (; e < end; ++e) {
        uint4 v = linv[(size_t)col[e] * 16 + cq];
        add8(acc, v);
    }

    float d = dinv[node];
    int c8 = cq << 3;
    float4 r0, r1;
    r0.x = tanhf(fmaf(acc[0], d, bias[c8 + 0]));
    r0.y = tanhf(fmaf(acc[1], d, bias[c8 + 1]));
    r0.z = tanhf(fmaf(acc[2], d, bias[c8 + 2]));
    r0.w = tanhf(fmaf(acc[3], d, bias[c8 + 3]));
    r1.x = tanhf(fmaf(acc[4], d, bias[c8 + 4]));
    r1.y = tanhf(fmaf(acc[5], d, bias[c8 + 5]));
    r1.z = tanhf(fmaf(acc[6], d, bias[c8 + 6]));
    r1.w = tanhf(fmaf(acc[7], d, bias[c8 + 7]));
    float4* op = (float4*)out + (size_t)node * 32 + (cq << 1);
    op[0] = r0;
    op[1] = r1;
}

// ---------------- Classifier ----------------

__global__ void classifier_kernel(const float* __restrict__ h, const float* __restrict__ Wc,
        const float* __restrict__ bc, float* __restrict__ out, int N, int Cout) {
    int idx = blockIdx.x * blockDim.x + threadIdx.x;
    if (idx >= N * Cout) return;
    int n = idx / Cout, c = idx - (idx / Cout) * Cout;
    float acc = bc[c];
    const float* hr = h + (size_t)n * H;
    #pragma unroll
    for (int k = 0; k < H; ++k) acc = fmaf(hr[k], Wc[k * Cout + c], acc);
    out[idx] = acc;
}

// ---------------- launch ----------------

extern "C" void kernel_launch(void* const* d_in, const int* in_sizes, int n_in,
                              void* d_out, int out_size, void* d_ws, size_t ws_size,
                              hipStream_t stream) {
    const float* x  = (const float*)d_in[0];
    const int* eidx = (const int*)d_in[1];
    const float* W1 = (const float*)d_in[2];
    const float* b1 = (const float*)d_in[3];
    const float* W2 = (const float*)d_in[4];
    const float* b2 = (const float*)d_in[5];
    const float* W3 = (const float*)d_in[6];
    const float* b3 = (const float*)d_in[7];
    const float* Wc = (const float*)d_in[8];
    const float* bc = (const float*)d_in[9];

    int N    = in_sizes[0] / H;       // 100000
    int E    = in_sizes[1] / 2;       // 3200000
    int Cout = in_sizes[8] / H;       // 40
    int nbk  = (N + 127) >> 7;        // 782 buckets

    const int* srcp = eidx;
    const int* dstp = eidx + E;

    float* out  = (float*)d_out;
    float* hOut = out + (size_t)N * Cout;   // h output region doubles as ping buffer

    char* p = (char*)d_ws;
    float* hAf      = (float*)p;  p += (size_t)N * H * 4;   // fp16 table lives here (half used)
    int*   col      = (int*)p;    p += (size_t)E * 4;
    int*   rowptr   = (int*)p;    p += (size_t)(N + 1) * 4;
    float* dinv     = (float*)p;  p += (size_t)N * 4;
    int*   bFill    = (int*)p;    p += 1024 * 4;
    int*   bBase    = (int*)p;    p += 1024 * 4;
    unsigned short* hA = (unsigned short*)hAf;
    int*   packed   = (int*)hAf;  // aliases hA: consumed by fine_kernel before gemm1 writes hA

    int gg = (N + 63) / 64;
    int gs = (N + 15) / 16;
    int gb = (E + 8191) / 8192;

    hipMemsetAsync(bFill, 0, (size_t)nbk * 4, stream);
    bin_kernel<<<gb, 256, 0, stream>>>(srcp, dstp, bFill, packed, E, nbk);
    bscan_kernel<<<1, 1024, 0, stream>>>(bFill, bBase, nbk, E, rowptr + N);
    fine_kernel<<<nbk, 256, 0, stream>>>(packed, bFill, bBase, rowptr, col, dinv, N);

    // layer 1
    gemm128_kernel<<<gg, 256, 0, stream>>>(x, W1, dinv, hA, N);
    spmm_kernel<<<gs, 256, 0, stream>>>(hA, rowptr, col, dinv, b1, hOut, N);
    // layer 2
    gemm128_kernel<<<gg, 256, 0, stream>>>(hOut, W2, dinv, hA, N);
    spmm_kernel<<<gs, 256, 0, stream>>>(hA, rowptr, col, dinv, b2, hOut, N);
    // layer 3
    gemm128_kernel<<<gg, 256, 0, stream>>>(hOut, W3, dinv, hA, N);
    spmm_kernel<<<gs, 256, 0, stream>>>(hA, rowptr, col, dinv, b3, hOut, N);
    // classifier
    classifier_kernel<<<(N * Cout + 255) / 256, 256, 0, stream>>>(hOut, Wc, bc, out, N, Cout);
}

// Round 5
// 814.866 us; speedup vs baseline: 2.1739x; 1.0910x over previous
//
#include <hip/hip_runtime.h>
#include <hip/hip_fp16.h>
#include <math.h>

#define H 128
#define BSTRIDE 5120            // packed entries per bucket (mean 4096, +16 sigma)

// ---------------- CSR build: bucketed counting sort ----------------
// bucket = dst >> 7 (128 nodes per bucket). packed entry = (local_dst<<17)|src.

__global__ __launch_bounds__(256) void bin_kernel(const int* __restrict__ src,
        const int* __restrict__ dst, int* __restrict__ bucketFill,
        int* __restrict__ packed, int E, int nbk) {
    __shared__ int hcnt[1024];
    __shared__ int base[1024];
    __shared__ int cur[1024];
    int tid = threadIdx.x;
    for (int i = tid; i < nbk; i += 256) { hcnt[i] = 0; cur[i] = 0; }
    __syncthreads();
    int e0 = blockIdx.x * 8192;
    int e1 = min(e0 + 8192, E);
    for (int e = e0 + tid; e < e1; e += 256)
        atomicAdd(&hcnt[dst[e] >> 7], 1);
    __syncthreads();
    for (int i = tid; i < nbk; i += 256) {
        int c = hcnt[i];
        base[i] = c ? atomicAdd(&bucketFill[i], c) : 0;   // claim contiguous chunk
    }
    __syncthreads();
    for (int e = e0 + tid; e < e1; e += 256) {
        int d = dst[e], s = src[e];
        int b = d >> 7;
        int r = atomicAdd(&cur[b], 1);
        packed[b * BSTRIDE + base[b] + r] = ((d & 127) << 17) | s;
    }
}

__global__ void bscan_kernel(const int* __restrict__ bucketFill, int* __restrict__ bucketBase,
                             int nbk, int E, int* __restrict__ rowptrN) {
    __shared__ int s[1024];
    int t = threadIdx.x;
    int v0 = (t < nbk) ? bucketFill[t] : 0;
    s[t] = v0;
    __syncthreads();
    for (int off = 1; off < 1024; off <<= 1) {
        int v = 0;
        if (t >= off) v = s[t - off];
        __syncthreads();
        s[t] += v;
        __syncthreads();
    }
    bucketBase[t] = s[t] - v0;                 // exclusive
    if (t == 0) rowptrN[0] = E;                // rowptr[N] = E
}

__global__ __launch_bounds__(256) void fine_kernel(const int* __restrict__ packed,
        const int* __restrict__ bucketFill, const int* __restrict__ bucketBase,
        int* __restrict__ rowptr, int* __restrict__ col, float* __restrict__ dinv, int N) {
    __shared__ int lcnt[128], lofs[128], lcur[128];
    int b = blockIdx.x;
    int tid = threadIdx.x;
    int m = bucketFill[b]; if (m > BSTRIDE) m = BSTRIDE;
    int base = bucketBase[b];
    int n0 = b << 7;
    if (tid < 128) lcnt[tid] = 0;
    __syncthreads();
    const int* pk = packed + (size_t)b * BSTRIDE;
    for (int i = tid; i < m; i += 256) atomicAdd(&lcnt[pk[i] >> 17], 1);
    __syncthreads();
    if (tid == 0) {
        int acc = 0;
        #pragma unroll 4
        for (int i = 0; i < 128; ++i) { lofs[i] = acc; acc += lcnt[i]; }
    }
    __syncthreads();
    if (tid < 128) {
        lcur[tid] = lofs[tid];
        int node = n0 + tid;
        if (node < N) {
            rowptr[node] = base + lofs[tid];
            dinv[node] = rsqrtf((float)(lcnt[tid] + 1));   // +1 self loop
        }
    }
    __syncthreads();
    for (int i = tid; i < m; i += 256) {
        int p = pk[i];
        int ld = p >> 17, s = p & 131071;
        int r = atomicAdd(&lcur[ld], 1);
        col[base + r] = s;
    }
}

// ---------------- GEMM: C[n,128] = fp16((A[n,128] @ W[128,128]) * scale[n]) ----------------

__device__ inline unsigned pack2(float x, float y) {
    __half2 h = __floats2half2_rn(x, y);
    return *(unsigned*)&h;
}

__global__ __launch_bounds__(256) void gemm128_kernel(const float* __restrict__ A,
        const float* __restrict__ W, const float* __restrict__ scale,
        unsigned short* __restrict__ C, int N) {
    __shared__ float As[64][H + 1];
    int tid = threadIdx.x;
    int r0 = blockIdx.x * 64;

    #pragma unroll
    for (int i = 0; i < 8; ++i) {
        int lin = tid + i * 256;          // float4 index, 2048 total
        int r = lin >> 5;                 // 32 float4 per row
        int c4 = (lin & 31) << 2;
        float4 v = make_float4(0.f, 0.f, 0.f, 0.f);
        if (r0 + r < N) v = *(const float4*)&A[(size_t)(r0 + r) * H + c4];
        As[r][c4 + 0] = v.x; As[r][c4 + 1] = v.y;
        As[r][c4 + 2] = v.z; As[r][c4 + 3] = v.w;
    }
    __syncthreads();

    int row = tid & 63;
    int c0 = __builtin_amdgcn_readfirstlane((tid >> 6) << 5);

    float acc[32];
    #pragma unroll
    for (int j = 0; j < 32; ++j) acc[j] = 0.f;

    for (int k = 0; k < H; ++k) {
        float a = As[row][k];
        #pragma unroll
        for (int j = 0; j < 32; ++j)
            acc[j] = fmaf(a, W[k * H + c0 + j], acc[j]);
    }

    int gr = r0 + row;
    if (gr < N) {
        float s = scale[gr];
        unsigned short* Crow = C + (size_t)gr * H;
        #pragma unroll
        for (int j = 0; j < 32; j += 8) {
            uint4 w;
            w.x = pack2(acc[j + 0] * s, acc[j + 1] * s);
            w.y = pack2(acc[j + 2] * s, acc[j + 3] * s);
            w.z = pack2(acc[j + 4] * s, acc[j + 5] * s);
            w.w = pack2(acc[j + 6] * s, acc[j + 7] * s);
            *(uint4*)&Crow[c0 + j] = w;
        }
    }
}

// ---------------- SpMM pull (fp16 gather table, fp32 accumulate/output) ----------------
// 16 threads/node, each owns 8 features (one 16B uint4 of the 256B fp16 row).

__device__ inline void add8(float* a, uint4 v) {
    float2 f;
    f = __half22float2(*(const __half2*)&v.x); a[0] += f.x; a[1] += f.y;
    f = __half22float2(*(const __half2*)&v.y); a[2] += f.x; a[3] += f.y;
    f = __half22float2(*(const __half2*)&v.z); a[4] += f.x; a[5] += f.y;
    f = __half22float2(*(const __half2*)&v.w); a[6] += f.x; a[7] += f.y;
}

__global__ __launch_bounds__(256) void spmm_kernel(const unsigned short* __restrict__ lin,
        const int* __restrict__ rowptr, const int* __restrict__ col,
        const float* __restrict__ dinv, const float* __restrict__ bias,
        float* __restrict__ out, int N) {
    int tid = threadIdx.x;
    int node = blockIdx.x * 16 + (tid >> 4);
    if (node >= N) return;
    int cq = tid & 15;                                 // 16B chunk within row

    int beg = rowptr[node];
    int end = rowptr[node + 1];

    const uint4* linv = (const uint4*)lin;

    float acc[8];
    {
        uint4 sv = linv[(size_t)node * 16 + cq];       // self loop (pre-scaled)
        float2 f;
        f = __half22float2(*(const __half2*)&sv.x); acc[0] = f.x; acc[1] = f.y;
        f = __half22float2(*(const __half2*)&sv.y); acc[2] = f.x; acc[3] = f.y;
        f = __half22float2(*(const __half2*)&sv.z); acc[4] = f.x; acc[5] = f.y;
        f = __half22float2(*(const __half2*)&sv.w); acc[6] = f.x; acc[7] = f.y;
    }

    int e = beg;
    for (; e + 4 <= end; e += 4) {
        int s0 = col[e], s1 = col[e + 1], s2 = col[e + 2], s3 = col[e + 3];
        uint4 v0 = linv[(size_t)s0 * 16 + cq];
        uint4 v1 = linv[(size_t)s1 * 16 + cq];
        uint4 v2 = linv[(size_t)s2 * 16 + cq];
        uint4 v3 = linv[(size_t)s3 * 16 + cq];
        add8(acc, v0);
        add8(acc, v1);
        add8(acc, v2);
        add8(acc, v3);
    }
    for (; e < end; ++e) {
        uint4 v = linv[(size_t)col[e] * 16 + cq];
        add8(acc, v);
    }

    float d = dinv[node];
    int c8 = cq << 3;
    float4 r0, r1;
    r0.x = tanhf(fmaf(acc[0], d, bias[c8 + 0]));
    r0.y = tanhf(fmaf(acc[1], d, bias[c8 + 1]));
    r0.z = tanhf(fmaf(acc[2], d, bias[c8 + 2]));
    r0.w = tanhf(fmaf(acc[3], d, bias[c8 + 3]));
    r1.x = tanhf(fmaf(acc[4], d, bias[c8 + 4]));
    r1.y = tanhf(fmaf(acc[5], d, bias[c8 + 5]));
    r1.z = tanhf(fmaf(acc[6], d, bias[c8 + 6]));
    r1.w = tanhf(fmaf(acc[7], d, bias[c8 + 7]));
    float4* op = (float4*)out + (size_t)node * 32 + (cq << 1);
    op[0] = r0;
    op[1] = r1;
}

// ---------------- Classifier: LDS-tiled, 64 rows/block, 4 groups x 10 cols ----------------

__global__ __launch_bounds__(256) void classifier_kernel(const float* __restrict__ h,
        const float* __restrict__ Wc, const float* __restrict__ bc,
        float* __restrict__ out, int N, int Cout) {
    __shared__ float As[64][H + 1];
    int tid = threadIdx.x;
    int r0 = blockIdx.x * 64;

    #pragma unroll
    for (int i = 0; i < 8; ++i) {
        int lin = tid + i * 256;          // float4 index, 2048 total
        int r = lin >> 5;
        int c4 = (lin & 31) << 2;
        float4 v = make_float4(0.f, 0.f, 0.f, 0.f);
        if (r0 + r < N) v = *(const float4*)&h[(size_t)(r0 + r) * H + c4];
        As[r][c4 + 0] = v.x; As[r][c4 + 1] = v.y;
        As[r][c4 + 2] = v.z; As[r][c4 + 3] = v.w;
    }
    __syncthreads();

    int row = tid & 63;
    int c0 = __builtin_amdgcn_readfirstlane((tid >> 6) * 10);   // 4 groups x 10 cols = 40

    float acc[10];
    #pragma unroll
    for (int j = 0; j < 10; ++j) acc[j] = bc[c0 + j];

    for (int k = 0; k < H; ++k) {
        float a = As[row][k];
        #pragma unroll
        for (int j = 0; j < 10; ++j)
            acc[j] = fmaf(a, Wc[k * Cout + c0 + j], acc[j]);
    }

    int gr = r0 + row;
    if (gr < N) {
        float* orow = out + (size_t)gr * Cout + c0;
        #pragma unroll
        for (int j = 0; j < 10; ++j) orow[j] = acc[j];
    }
}

// ---------------- launch ----------------

extern "C" void kernel_launch(void* const* d_in, const int* in_sizes, int n_in,
                              void* d_out, int out_size, void* d_ws, size_t ws_size,
                              hipStream_t stream) {
    const float* x  = (const float*)d_in[0];
    const int* eidx = (const int*)d_in[1];
    const float* W1 = (const float*)d_in[2];
    const float* b1 = (const float*)d_in[3];
    const float* W2 = (const float*)d_in[4];
    const float* b2 = (const float*)d_in[5];
    const float* W3 = (const float*)d_in[6];
    const float* b3 = (const float*)d_in[7];
    const float* Wc = (const float*)d_in[8];
    const float* bc = (const float*)d_in[9];

    int N    = in_sizes[0] / H;       // 100000
    int E    = in_sizes[1] / 2;       // 3200000
    int Cout = in_sizes[8] / H;       // 40
    int nbk  = (N + 127) >> 7;        // 782 buckets

    const int* srcp = eidx;
    const int* dstp = eidx + E;

    float* out  = (float*)d_out;
    float* hOut = out + (size_t)N * Cout;   // h output region doubles as ping buffer

    char* p = (char*)d_ws;
    float* hAf      = (float*)p;  p += (size_t)N * H * 4;   // fp16 table lives here (half used)
    int*   col      = (int*)p;    p += (size_t)E * 4;
    int*   rowptr   = (int*)p;    p += (size_t)(N + 1) * 4;
    float* dinv     = (float*)p;  p += (size_t)N * 4;
    int*   bFill    = (int*)p;    p += 1024 * 4;
    int*   bBase    = (int*)p;    p += 1024 * 4;
    unsigned short* hA = (unsigned short*)hAf;
    int*   packed   = (int*)hAf;  // aliases hA: consumed by fine_kernel before gemm1 writes hA

    int gg = (N + 63) / 64;
    int gs = (N + 15) / 16;
    int gb = (E + 8191) / 8192;

    hipMemsetAsync(bFill, 0, (size_t)nbk * 4, stream);
    bin_kernel<<<gb, 256, 0, stream>>>(srcp, dstp, bFill, packed, E, nbk);
    bscan_kernel<<<1, 1024, 0, stream>>>(bFill, bBase, nbk, E, rowptr + N);
    fine_kernel<<<nbk, 256, 0, stream>>>(packed, bFill, bBase, rowptr, col, dinv, N);

    // layer 1
    gemm128_kernel<<<gg, 256, 0, stream>>>(x, W1, dinv, hA, N);
    spmm_kernel<<<gs, 256, 0, stream>>>(hA, rowptr, col, dinv, b1, hOut, N);
    // layer 2
    gemm128_kernel<<<gg, 256, 0, stream>>>(hOut, W2, dinv, hA, N);
    spmm_kernel<<<gs, 256, 0, stream>>>(hA, rowptr, col, dinv, b2, hOut, N);
    // layer 3
    gemm128_kernel<<<gg, 256, 0, stream>>>(hOut, W3, dinv, hA, N);
    spmm_kernel<<<gs, 256, 0, stream>>>(hA, rowptr, col, dinv, b3, hOut, N);
    // classifier
    classifier_kernel<<<gg, 256, 0, stream>>>(hOut, Wc, bc, out, N, Cout);
}